// Round 1
// baseline (1260.787 us; speedup 1.0000x reference)
//
#include <hip/hip_runtime.h>
#include <math.h>

#define FEAT 256
#define RANKK 16
#define SBLK 4096   // elements per selection block (256 threads x 16)

// ---------------- proj = x @ W^T  (double accumulation) ----------------
__global__ void proj_kernel(const float* __restrict__ x, const float* __restrict__ Wm,
                            double* __restrict__ proj, int n_nodes) {
    __shared__ float Ws[RANKK][FEAT + 1];
    for (int t = threadIdx.x; t < RANKK * FEAT; t += blockDim.x)
        Ws[t >> 8][t & 255] = Wm[t];
    __syncthreads();
    int gid = blockIdx.x * blockDim.x + threadIdx.x;
    int node = gid >> 4;
    int r = gid & 15;
    if (node >= n_nodes) return;
    const float* xr = x + (size_t)node * FEAT;
    double acc = 0.0;
    #pragma unroll 8
    for (int j = 0; j < FEAT; ++j)
        acc += (double)xr[j] * (double)Ws[r][j];
    proj[(size_t)node * RANKK + r] = acc;
}

// ------------- scores + edge sums/counts + level-1 histogram -------------
__global__ void score_kernel(const double* __restrict__ proj, const float* __restrict__ ef,
                             const int* __restrict__ V_idx, const int* __restrict__ E_idx,
                             const int* __restrict__ edge_ids,
                             float* __restrict__ scores, float* __restrict__ e_ssum,
                             unsigned* __restrict__ e_cnt, unsigned* __restrict__ hist1, int nnz) {
    __shared__ unsigned h[4096];
    for (int t = threadIdx.x; t < 4096; t += blockDim.x) h[t] = 0;
    __syncthreads();
    for (int i = blockIdx.x * blockDim.x + threadIdx.x; i < nnz; i += gridDim.x * blockDim.x) {
        int v = V_idx[i];
        int e = E_idx[i];
        int eid = edge_ids[e];
        const double* p = proj + (size_t)v * RANKK;
        const float* f = ef + (size_t)eid * RANKK;
        double acc = 0.0;
        #pragma unroll
        for (int r = 0; r < RANKK; ++r) acc += p[r] * (double)f[r];
        double s = 1.0 / (1.0 + exp(-acc));
        float sf = (float)s;
        scores[i] = sf;
        atomicAdd(&e_ssum[e], sf);
        atomicAdd(&e_cnt[e], 1u);
        atomicAdd(&h[__float_as_uint(sf) >> 20], 1u);
    }
    __syncthreads();
    for (int t = threadIdx.x; t < 4096; t += blockDim.x)
        if (h[t]) atomicAdd(&hist1[t], h[t]);
}

// ---------------- radix-select scan (single thread, tiny) ----------------
// sel[0]=k_rem, sel[1]=prefix bits, sel[2]=T (exact bits), sel[3]=m (ties to keep)
__global__ void scan_kernel(const unsigned* __restrict__ hist, int nbins,
                            unsigned* __restrict__ sel, const int* __restrict__ kptr, int level) {
    if (threadIdx.x != 0 || blockIdx.x != 0) return;
    unsigned krem = (level == 0) ? (unsigned)(*kptr) : sel[0];
    unsigned cum = 0;
    int b = nbins - 1;
    while (b > 0) {
        unsigned c = hist[b];
        if (cum + c >= krem) break;
        cum += c;
        --b;
    }
    unsigned newk = krem - cum;
    sel[0] = newk;
    if (level == 0) {
        sel[1] = ((unsigned)b) << 20;
    } else if (level == 1) {
        sel[1] |= ((unsigned)b) << 8;
    } else {
        unsigned T = sel[1] | (unsigned)b;
        sel[2] = T;
        sel[3] = newk;   // number of ==T elements to keep (lowest index first)
    }
}

// ------------- level-2 / level-3 histogram passes over scores -------------
__global__ void hist_pass(const float* __restrict__ scores, const unsigned* __restrict__ sel,
                          unsigned* __restrict__ hist, int nnz, int mode) {
    __shared__ unsigned h[4096];
    const int nb = (mode == 1) ? 4096 : 256;
    for (int t = threadIdx.x; t < nb; t += blockDim.x) h[t] = 0;
    __syncthreads();
    unsigned pref = sel[1];
    for (int i = blockIdx.x * blockDim.x + threadIdx.x; i < nnz; i += gridDim.x * blockDim.x) {
        unsigned bits = __float_as_uint(scores[i]);
        if (mode == 1) {
            if ((bits >> 20) == (pref >> 20)) atomicAdd(&h[(bits >> 8) & 0xFFF], 1u);
        } else {
            if ((bits >> 8) == (pref >> 8)) atomicAdd(&h[bits & 0xFF], 1u);
        }
    }
    __syncthreads();
    for (int t = threadIdx.x; t < nb; t += blockDim.x)
        if (h[t]) atomicAdd(&hist[t], h[t]);
}

// ------------- per-block count of elements exactly == T -------------
__global__ void eq_count(const float* __restrict__ scores, const unsigned* __restrict__ sel,
                         unsigned* __restrict__ blockCnt, int nnz) {
    __shared__ unsigned red[256];
    unsigned T = sel[2];
    int base = blockIdx.x * SBLK + threadIdx.x * 16;
    unsigned cnt = 0;
    #pragma unroll
    for (int s = 0; s < 16; ++s) {
        int i = base + s;
        if (i < nnz) cnt += (__float_as_uint(scores[i]) == T);
    }
    red[threadIdx.x] = cnt;
    __syncthreads();
    for (int off = 128; off > 0; off >>= 1) {
        if (threadIdx.x < off) red[threadIdx.x] += red[threadIdx.x + off];
        __syncthreads();
    }
    if (threadIdx.x == 0) blockCnt[blockIdx.x] = red[0];
}

// serial exclusive scan over block counts (977 entries -> trivial)
__global__ void scan_blocks(unsigned* __restrict__ blockCnt, int nblocks) {
    if (threadIdx.x != 0 || blockIdx.x != 0) return;
    unsigned run = 0;
    for (int j = 0; j < nblocks; ++j) {
        unsigned c = blockCnt[j];
        blockCnt[j] = run;
        run += c;
    }
}

// ------------- write hard/soft + edge hard-sum, exact tie handling -------------
__global__ void write_hard(const float* __restrict__ scores, const unsigned* __restrict__ sel,
                           const unsigned* __restrict__ blockCnt,
                           float* __restrict__ hard, float* __restrict__ soft,
                           const int* __restrict__ E_idx, unsigned* __restrict__ e_hsum, int nnz) {
    __shared__ unsigned ps[256];
    unsigned T = sel[2];
    unsigned m = sel[3];
    int base = blockIdx.x * SBLK + threadIdx.x * 16;

    // pass 1: count my equals
    unsigned cnt = 0;
    #pragma unroll
    for (int s = 0; s < 16; ++s) {
        int i = base + s;
        if (i < nnz) cnt += (__float_as_uint(scores[i]) == T);
    }
    ps[threadIdx.x] = cnt;
    __syncthreads();
    // Hillis-Steele inclusive scan over 256 thread counts
    for (int off = 1; off < 256; off <<= 1) {
        unsigned v = 0;
        if (threadIdx.x >= (unsigned)off) v = ps[threadIdx.x - off];
        __syncthreads();
        ps[threadIdx.x] += v;
        __syncthreads();
    }
    unsigned running = blockCnt[blockIdx.x] + ps[threadIdx.x] - cnt;

    // pass 2: classify in index order
    #pragma unroll
    for (int s = 0; s < 16; ++s) {
        int i = base + s;
        if (i >= nnz) break;
        unsigned bits = __float_as_uint(scores[i]);
        bool keep;
        if (bits > T) {
            keep = true;
        } else if (bits == T) {
            keep = (running < m);
            ++running;
        } else {
            keep = false;
        }
        float hv = keep ? 1.0f : 0.0f;
        hard[i] = hv;
        soft[i] = hv;   // forward: soft == hard exactly
        if (keep) atomicAdd(&e_hsum[E_idx[i]], 1u);
    }
}

// ---------------- per-hyperedge finalize ----------------
__global__ void finalize_edges(const float* __restrict__ ssum, const unsigned* __restrict__ cnt,
                               const unsigned* __restrict__ hsum,
                               float* __restrict__ eprob, float* __restrict__ esoft,
                               float* __restrict__ ehard, int nhe) {
    int j = blockIdx.x * blockDim.x + threadIdx.x;
    if (j >= nhe) return;
    float c = fmaxf((float)cnt[j], 1.0f);
    eprob[j] = ssum[j] / c;
    esoft[j] = (float)hsum[j] / c;
    ehard[j] = (hsum[j] > 0) ? 1.0f : 0.0f;
}

extern "C" void kernel_launch(void* const* d_in, const int* in_sizes, int n_in,
                              void* d_out, int out_size, void* d_ws, size_t ws_size,
                              hipStream_t stream) {
    const float* x        = (const float*)d_in[0];
    const float* Wm       = (const float*)d_in[1];
    const float* ef       = (const float*)d_in[2];
    const int*   V_idx    = (const int*)d_in[3];
    const int*   E_idx    = (const int*)d_in[4];
    const int*   edge_ids = (const int*)d_in[5];
    const int*   kptr     = (const int*)d_in[6];   // first 4 bytes give k for int32/int64

    const int nnz     = in_sizes[3];
    const int nhe     = in_sizes[5];
    const int n_nodes = in_sizes[0] / FEAT;

    float* out    = (float*)d_out;
    float* scores = out;
    float* soft   = out + (size_t)nnz;
    float* hard   = out + 2 * (size_t)nnz;
    float* eprob  = out + 3 * (size_t)nnz;
    float* esoft  = eprob + nhe;
    float* ehard  = esoft + nhe;

    const int nb4 = (nnz + SBLK - 1) / SBLK;

    // workspace layout
    char* w = (char*)d_ws;
    size_t projBytes = (size_t)n_nodes * RANKK * sizeof(double);
    size_t auxBytes  = (size_t)(3 * nhe + 4096 + 4096 + 256 + nb4 + 8) * 4 + 256;
    double* proj;
    size_t zoff;
    if (ws_size >= projBytes + auxBytes) {
        proj = (double*)w;
        zoff = projBytes;
    } else {
        // stage proj in the 'soft' output region (16 MB >= 12.8 MB); it is
        // consumed by score_kernel before write_hard overwrites soft.
        proj = (double*)soft;
        zoff = 0;
    }
    float*    e_ssum   = (float*)(w + zoff);
    unsigned* e_cnt    = (unsigned*)(e_ssum + nhe);
    unsigned* e_hsum   = e_cnt + nhe;
    unsigned* hist1    = e_hsum + nhe;
    unsigned* hist2    = hist1 + 4096;
    unsigned* hist3    = hist2 + 4096;
    unsigned* blockCnt = hist3 + 256;
    unsigned* sel      = blockCnt + nb4;
    size_t zbytes = (size_t)((char*)(sel + 8) - (char*)e_ssum);
    hipMemsetAsync(e_ssum, 0, zbytes, stream);

    proj_kernel<<<(n_nodes * RANKK + 255) / 256, 256, 0, stream>>>(x, Wm, proj, n_nodes);
    score_kernel<<<2048, 256, 0, stream>>>(proj, ef, V_idx, E_idx, edge_ids,
                                           scores, e_ssum, e_cnt, hist1, nnz);
    scan_kernel<<<1, 1, 0, stream>>>(hist1, 4096, sel, kptr, 0);
    hist_pass<<<2048, 256, 0, stream>>>(scores, sel, hist2, nnz, 1);
    scan_kernel<<<1, 1, 0, stream>>>(hist2, 4096, sel, kptr, 1);
    hist_pass<<<2048, 256, 0, stream>>>(scores, sel, hist3, nnz, 2);
    scan_kernel<<<1, 1, 0, stream>>>(hist3, 256, sel, kptr, 2);
    eq_count<<<nb4, 256, 0, stream>>>(scores, sel, blockCnt, nnz);
    scan_blocks<<<1, 1, 0, stream>>>(blockCnt, nb4);
    write_hard<<<nb4, 256, 0, stream>>>(scores, sel, blockCnt, hard, soft, E_idx, e_hsum, nnz);
    finalize_edges<<<(nhe + 255) / 256, 256, 0, stream>>>(e_ssum, e_cnt, e_hsum,
                                                          eprob, esoft, ehard, nhe);
}